// Round 5
// baseline (491.167 us; speedup 1.0000x reference)
//
#include <hip/hip_runtime.h>

// LorentzBlock: B=2, L=2048, D=768, H=12, DH=64, DFF=3072
// R15: ffn2 split-K x4 -> x8 (grid (6,32,8)=1536 blocks, 6/CU, K=768/chunk).
// R14 counters: ffn2 90us, Occupancy 26% (3 blk/CU), MfmaUtil 16%, HBM 31%
// -> still latency-bound on the per-K-iter vmcnt(0) drain; more independent
// blocks is the proven lever (worked R11 ffn2 x4, R13 flash KV-split).
// Also Wo split-K x2 -> x4 (768 blocks, 3/CU). Flash-decode unchanged.

typedef unsigned short u16;
typedef __bf16 bfrag __attribute__((ext_vector_type(8)));
typedef float f32x4 __attribute__((ext_vector_type(4)));

#define MFMA(a, b, c) __builtin_amdgcn_mfma_f32_16x16x32_bf16(a, b, c, 0, 0, 0)
#define NEG_BIG (-30000.0f)
#define ASYNC16(g, l)                                                        \
  __builtin_amdgcn_global_load_lds(                                          \
      (const __attribute__((address_space(1))) unsigned int*)(g),            \
      (__attribute__((address_space(3))) unsigned int*)(l), 16, 0, 0)

__device__ __forceinline__ float bf2f(u16 u) {
  unsigned int v = ((unsigned int)u) << 16;
  float f; __builtin_memcpy(&f, &v, 4); return f;
}
__device__ __forceinline__ u16 f2bf(float f) {
  unsigned int v; __builtin_memcpy(&v, &f, 4);
  v += 0x7fffu + ((v >> 16) & 1u);   // RNE
  return (u16)(v >> 16);
}
__device__ __forceinline__ bfrag ldfrag(const u16* p) {
  bfrag v; __builtin_memcpy(&v, p, 16); return v;
}

// ---------------------------------------------------------------------------
// Mask canonicalization -> float[768].
// ---------------------------------------------------------------------------
__global__ __launch_bounds__(256) void mask_conv_k(const void* __restrict__ mask,
                                                   float* __restrict__ mfl) {
  __shared__ int msh;
  if (threadIdx.x == 0) msh = 0;
  __syncthreads();
  const unsigned int* w = (const unsigned int*)mask;
  if (threadIdx.x < 192) {
    const unsigned int v = w[threadIdx.x];
    if ((v & 0xFFFFu) == 0x3F80u) atomicOr(&msh, 4);
    else if (v == 0x3F800000u) atomicOr(&msh, 2);
    else if (v >= 2u) atomicOr(&msh, 1);
  }
  __syncthreads();
  const int m = msh;
  const int mode = (m & 4) ? 3 : (m & 2) ? 2 : (m & 1) ? 1 : 0;
  for (int i = threadIdx.x; i < 768; i += 256) {
    int b;
    if (mode == 3) b = ((const u16*)mask)[i] != 0;
    else if (mode == 2) b = ((const float*)mask)[i] != 0.0f;
    else if (mode == 1) b = ((const unsigned char*)mask)[i] != 0;
    else b = ((const int*)mask)[i] != 0;
    mfl[i] = (float)b;
  }
}

// ---------------------------------------------------------------------------
// Convert fp32 weight segments -> bf16 arena. mmode: 0 none, 1 *m[k],
// 2 *(1-m[k]) with k = i % 768 (mask fold for w1_t / w1_s).
// ---------------------------------------------------------------------------
struct Segs {
  const void* src[14];
  int off[14];
  int n[14];
  int mmode[14];
};

__global__ __launch_bounds__(256) void convert_k(Segs segs, u16* __restrict__ dstb,
                                                 const float* __restrict__ mfl) {
  const int seg = blockIdx.y;
  const int n = segs.n[seg];
  const int mm = segs.mmode[seg];
  u16* dst = dstb + segs.off[seg];
  const float* src = (const float*)segs.src[seg];
  for (int i = (blockIdx.x * 256 + threadIdx.x) * 4; i < n; i += gridDim.x * 1024) {
    float4 v;
    __builtin_memcpy(&v, src + i, 16);
    if (mm) {
      const int k = i % 768;
      float m0 = mfl[k], m1 = mfl[k + 1], m2 = mfl[k + 2], m3 = mfl[k + 3];
      if (mm == 2) { m0 = 1.f - m0; m1 = 1.f - m1; m2 = 1.f - m2; m3 = 1.f - m3; }
      v.x *= m0; v.y *= m1; v.z *= m2; v.w *= m3;
    }
    dst[i] = f2bf(v.x); dst[i + 1] = f2bf(v.y);
    dst[i + 2] = f2bf(v.z); dst[i + 3] = f2bf(v.w);
  }
}

// ---------------------------------------------------------------------------
// Minkowski LayerNorm. fp32 input, bf16 output. Optionally copies the raw
// input row to Xcopy (fp32) -- seeds d_out with x for the Wo split-K atomics.
// ---------------------------------------------------------------------------
__global__ __launch_bounds__(256) void mink_norm_k(
    const float* __restrict__ X, const float* __restrict__ mf,
    const u16* __restrict__ w, const u16* __restrict__ bias,
    u16* __restrict__ Y, float* __restrict__ Xcopy) {
  __shared__ float red[8];
  const int row = blockIdx.x, tid = threadIdx.x;
  const int wid = tid >> 6, lane = tid & 63;
  const size_t roff = (size_t)row * 768;

  float xv[3], mv[3];
  int idx[3];
#pragma unroll
  for (int i = 0; i < 3; i++) {
    idx[i] = tid + i * 256;
    xv[i] = X[roff + idx[i]];
    mv[i] = mf[idx[i]];
  }
  if (Xcopy) {
#pragma unroll
    for (int i = 0; i < 3; i++) Xcopy[roff + idx[i]] = xv[i];
  }
  float s = xv[0] + xv[1] + xv[2];
#pragma unroll
  for (int o = 32; o >= 1; o >>= 1) s += __shfl_xor(s, o, 64);
  if (lane == 0) red[wid] = s;
  __syncthreads();
  const float mean = (red[0] + red[1] + red[2] + red[3]) * (1.0f / 768.0f);
  __syncthreads();

  float xc[3], ss = 0.0f, sm = 0.0f;
#pragma unroll
  for (int i = 0; i < 3; i++) {
    xc[i] = xv[i] - mean;
    ss += xc[i] * xc[i];
    sm += xc[i] * xc[i] * mv[i];
  }
#pragma unroll
  for (int o = 32; o >= 1; o >>= 1) {
    ss += __shfl_xor(ss, o, 64);
    sm += __shfl_xor(sm, o, 64);
  }
  if (lane == 0) { red[wid] = ss; red[4 + wid] = sm; }
  __syncthreads();
  const float sumsq = red[0] + red[1] + red[2] + red[3];
  const float summ = red[4] + red[5] + red[6] + red[7];
  const float var = sumsq * (1.0f / 768.0f);
  const float eta = sumsq - 2.0f * summ;
  const float rs = 1.0f / sqrtf(var + 1e-5f);
  const float re = 1.0f / sqrtf(fabsf(eta) + 1e-5f);

#pragma unroll
  for (int i = 0; i < 3; i++) {
    const float xn = xc[i] * 0.5f * (rs + re);
    Y[roff + idx[i]] = f2bf(bf2f(w[idx[i]]) * xn + bf2f(bias[idx[i]]));
  }
}

// ---------------------------------------------------------------------------
// Q Lorentz correction, in place. 4 rows per block (one per wave).
// ---------------------------------------------------------------------------
__global__ __launch_bounds__(256) void qcorr_k(u16* __restrict__ Q,
                                               const float* __restrict__ mf) {
  const int idx = blockIdx.x * 4 + (threadIdx.x >> 6);  // (b*2048+l)*12+h
  const int t = threadIdx.x & 63;
  const int h = idx % 12;
  const int bl = idx / 12;
  const size_t off = (size_t)bl * 768 + h * 64 + t;
  const float q = bf2f(Q[off]);
  const float m = mf[h * 64 + t];
  float q2 = q * q, qm2 = q * q * m;
#pragma unroll
  for (int o = 32; o >= 1; o >>= 1) {
    q2 += __shfl_xor(q2, o, 64);
    qm2 += __shfl_xor(qm2, o, 64);
  }
  const float qn = sqrtf(q2), qtn = sqrtf(qm2);
  const float sf = (qtn > 1e-6f) ? qn / fmaxf(qtn, 1e-8f) : 0.0f;
  Q[off] = f2bf(q * (1.0f - 0.5f * sf * m) * 0.125f);
}

// ---------------------------------------------------------------------------
// 128x128 MFMA GEMM core (m97 structure). As/Bs unpadded [128][32],
// global_load_lds 16B staging, 16 MFMA + 8 ds_read_b128 per wave per K-iter.
// Wave grid 2x2, each wave 64x64 (4x4 tiles). acc[4][4] per lane.
// ldb = B row stride (== K unless K-split).
// ---------------------------------------------------------------------------
__device__ __forceinline__ void gemm128_loop(
    const u16* __restrict__ Ab, const u16* __restrict__ Wb2,
    int K, int lda, int ldb, u16 (*As)[32], u16 (*Bs)[32], f32x4 acc[4][4]) {
  const int tid = threadIdx.x;
  const int wid = tid >> 6, lane = tid & 63;
  const int lr = lane & 15, lq = lane >> 4;
  const int srow = wid * 32 + (lane >> 2);
  const int scol = (lane & 3) * 8;
  const u16* ga0 = Ab + (size_t)srow * lda + scol;
  const u16* ga1 = Ab + (size_t)(srow + 16) * lda + scol;
  const u16* gb0 = Wb2 + (size_t)srow * ldb + scol;
  const u16* gb1 = Wb2 + (size_t)(srow + 16) * ldb + scol;
  u16* la0 = &As[wid * 32][0];
  u16* la1 = &As[wid * 32 + 16][0];
  u16* lb0 = &Bs[wid * 32][0];
  u16* lb1 = &Bs[wid * 32 + 16][0];
  const int wr = (wid >> 1) * 64, wc = (wid & 1) * 64;

  for (int k0 = 0; k0 < K; k0 += 32) {
    __syncthreads();            // prior iter's LDS reads complete
    ASYNC16(ga0 + k0, la0);
    ASYNC16(ga1 + k0, la1);
    ASYNC16(gb0 + k0, lb0);
    ASYNC16(gb1 + k0, lb1);
    __syncthreads();            // compiler drains vmcnt before barrier
    bfrag af[4], bf4[4];
#pragma unroll
    for (int i = 0; i < 4; i++) af[i] = ldfrag(&As[wr + i * 16 + lr][lq * 8]);
#pragma unroll
    for (int j = 0; j < 4; j++) bf4[j] = ldfrag(&Bs[wc + j * 16 + lr][lq * 8]);
#pragma unroll
    for (int i = 0; i < 4; i++)
#pragma unroll
      for (int j = 0; j < 4; j++)
        acc[i][j] = MFMA(af[i], bf4[j], acc[i][j]);
  }
}

// ---------------------------------------------------------------------------
// Fused multi-segment GEMM, bf16 out: C_seg = epi(A @ Wseg^T).
// Segments partition blockIdx.x. epi: 0 none, 2 gelu(exact), 3 silu.
// ---------------------------------------------------------------------------
struct GSeg { const u16* W; u16* C; int ldc; int nblk; int epi; };
struct GArgs { GSeg s[3]; };

__global__ __launch_bounds__(256) void gemm128_fused(
    const u16* __restrict__ A, int lda, int K, GArgs args) {
  __shared__ __align__(16) u16 As[128][32];
  __shared__ __align__(16) u16 Bs[128][32];
  int cb = blockIdx.x, seg = 0;
  while (cb >= args.s[seg].nblk) { cb -= args.s[seg].nblk; seg++; }
  const GSeg g = args.s[seg];
  const int rowb = blockIdx.y * 128, colb = cb * 128;
  f32x4 acc[4][4] = {};
  gemm128_loop(A + (size_t)rowb * lda, g.W + (size_t)colb * K, K, lda, K,
               As, Bs, acc);

  const int lane = threadIdx.x & 63, wid = threadIdx.x >> 6;
  const int lr = lane & 15, lq = lane >> 4;
  const int wr = (wid >> 1) * 64, wc = (wid & 1) * 64;
#pragma unroll
  for (int i = 0; i < 4; i++)
#pragma unroll
    for (int j = 0; j < 4; j++)
#pragma unroll
      for (int r = 0; r < 4; r++) {
        const int row = rowb + wr + i * 16 + lq * 4 + r;
        const int col = colb + wc + j * 16 + lr;
        float v = acc[i][j][r];
        if (g.epi == 2) v = 0.5f * v * (1.0f + erff(v * 0.70710678118654752f));
        else if (g.epi == 3) v = v / (1.0f + __expf(-v));
        g.C[(size_t)row * g.ldc + col] = f2bf(v);
      }
}

// ---------------------------------------------------------------------------
// Wo projection split-K x4: Out += att @ Wo^T partial. Out (d_out) holds x
// (seeded by mink_norm#1). blockIdx.z selects K-quarter (K=192 each).
// 768 blocks, 3/CU.
// ---------------------------------------------------------------------------
__global__ __launch_bounds__(256) void gemm128_wo_splitk(
    const u16* __restrict__ A, const u16* __restrict__ W,
    float* __restrict__ Out) {
  __shared__ __align__(16) u16 As[128][32];
  __shared__ __align__(16) u16 Bs[128][32];
  const int rowb = blockIdx.y * 128, colb = blockIdx.x * 128;
  const int z = blockIdx.z;
  f32x4 acc[4][4] = {};
  gemm128_loop(A + (size_t)rowb * 768 + z * 192,
               W + (size_t)colb * 768 + z * 192, 192, 768, 768, As, Bs, acc);

  const int lane = threadIdx.x & 63, wid = threadIdx.x >> 6;
  const int lr = lane & 15, lq = lane >> 4;
  const int wr = (wid >> 1) * 64, wc = (wid & 1) * 64;
#pragma unroll
  for (int i = 0; i < 4; i++)
#pragma unroll
    for (int j = 0; j < 4; j++)
#pragma unroll
      for (int r = 0; r < 4; r++) {
        const int row = rowb + wr + i * 16 + lq * 4 + r;
        const int col = colb + wc + j * 16 + lr;
        atomicAdd(&Out[(size_t)row * 768 + col], acc[i][j][r]);
      }
}

// ---------------------------------------------------------------------------
// FFN2 split-K x8: Out += 0.5 * partial. Out (d_out) already holds x1.
// z = seg*2 + khalf; seg: 0/1 = h1@w2 K-halves of [0,3072), 2 = ht@w2t,
// 3 = hs@w2s; khalf picks 768-wide K chunk within the segment.
// grid (6,32,8) = 1536 blocks (6/CU) vs 768 in R14 (latency cure).
// ---------------------------------------------------------------------------
__global__ __launch_bounds__(256) void ffn2_splitk(
    const u16* __restrict__ H1, const u16* __restrict__ Ht,
    const u16* __restrict__ Hs, const u16* __restrict__ W2,
    const u16* __restrict__ W2t, const u16* __restrict__ W2s,
    float* __restrict__ Out) {
  __shared__ __align__(16) u16 As[128][32];
  __shared__ __align__(16) u16 Bs[128][32];
  const int rowb = blockIdx.y * 128, colb = blockIdx.x * 128;
  const int seg = blockIdx.z >> 1;
  const int kh = (blockIdx.z & 1) * 768;
  f32x4 acc[4][4] = {};
  if (seg == 0)
    gemm128_loop(H1 + (size_t)rowb * 3072 + kh,
                 W2 + (size_t)colb * 3072 + kh, 768, 3072, 3072, As, Bs, acc);
  else if (seg == 1)
    gemm128_loop(H1 + (size_t)rowb * 3072 + 1536 + kh,
                 W2 + (size_t)colb * 3072 + 1536 + kh, 768, 3072, 3072,
                 As, Bs, acc);
  else if (seg == 2)
    gemm128_loop(Ht + (size_t)rowb * 1536 + kh,
                 W2t + (size_t)colb * 1536 + kh, 768, 1536, 1536, As, Bs, acc);
  else
    gemm128_loop(Hs + (size_t)rowb * 1536 + kh,
                 W2s + (size_t)colb * 1536 + kh, 768, 1536, 1536, As, Bs, acc);

  const int lane = threadIdx.x & 63, wid = threadIdx.x >> 6;
  const int lr = lane & 15, lq = lane >> 4;
  const int wr = (wid >> 1) * 64, wc = (wid & 1) * 64;
#pragma unroll
  for (int i = 0; i < 4; i++)
#pragma unroll
    for (int j = 0; j < 4; j++)
#pragma unroll
      for (int r = 0; r < 4; r++) {
        const int row = rowb + wr + i * 16 + lq * 4 + r;
        const int col = colb + wc + j * 16 + lr;
        atomicAdd(&Out[(size_t)row * 768 + col], 0.5f * acc[i][j][r]);
      }
}

// ---------------------------------------------------------------------------
// Flash attention producer, causal, KV-split. QBLK=64, 4 waves, 256 thr.
// Per bh: 80 chunks. qt = q-tile (0..31), chunk covers kv tiles
// [c*8, min(c*8+8, qt+1)). qt<8: single chunk, writes final bf16 att.
// qt>=8: writes fp32 unnormalized O + (m,l) partial to slot
//   s = bh*72 + off(qt) + c;  slots 0..1535 in Pn (n1h), rest in Ph (hs);
//   m/l at Ph + 786432 floats, 128 floats per slot.
// ---------------------------------------------------------------------------
__global__ __launch_bounds__(256) void flash_attn_k(
    const u16* __restrict__ Qc, const u16* __restrict__ Kb,
    const u16* __restrict__ Vb, u16* __restrict__ O,
    float* __restrict__ Pn, float* __restrict__ Ph) {
  __shared__ __align__(16) u16 Ks[64][40];
  __shared__ __align__(16) u16 Vt[64][72];
  __shared__ __align__(16) u16 Ps[4][16][72];
  const int tid = threadIdx.x, wid = tid >> 6, lane = tid & 63;
  const int lr = lane & 15, lq = lane >> 4;

  // decode blockIdx.x -> (qt, c); qt descending so long chunks launch first
  int bx = blockIdx.x, qt = 0, c = 0;
  for (int q = 31; q >= 0; --q) {
    const int nc = (q < 8) ? 1 : (q / 8 + 1);
    if (bx < nc) { qt = q; c = bx; break; }
    bx -= nc;
  }
  const int nt = qt + 1;
  const int t0 = c * 8;
  const int t1 = (t0 + 8 < nt) ? t0 + 8 : nt;

  const int qb = qt * 64;
  const int bh = blockIdx.y;
  const int b = bh / 12, h = bh % 12;
  const int q0 = qb + wid * 16;
  const size_t base = (size_t)b * 2048 * 768 + h * 64;

  bfrag aq[2];
  aq[0] = ldfrag(Qc + base + (size_t)(q0 + lr) * 768 + lq * 8);
  aq[1] = ldfrag(Qc + base + (size_t)(q0 + lr) * 768 + 32 + lq * 8);

  f32x4 o[4] = {};
  float mrow[4] = {NEG_BIG, NEG_BIG, NEG_BIG, NEG_BIG};
  float lrow[4] = {0.0f, 0.0f, 0.0f, 0.0f};

  const int krow = tid >> 3;        // 0..31
  const int kcol = (tid & 7) * 8;
  const int vkey = tid & 31;
  const int vdg = tid >> 5;         // 0..7

  const u16* kp = Kb + base + (size_t)(t0 * 64 + krow) * 768 + kcol;
  const u16* vp = Vb + base + (size_t)(t0 * 64 + vkey) * 768 + vdg * 8;

  uint4 kv0, kv1, vv0, vv1;
  __builtin_memcpy(&kv0, kp, 16);
  __builtin_memcpy(&kv1, kp + (size_t)32 * 768, 16);
  __builtin_memcpy(&vv0, vp, 16);
  __builtin_memcpy(&vv1, vp + (size_t)32 * 768, 16);

  for (int kt = t0; kt < t1; kt++) {
    __syncthreads();
    __builtin_memcpy(&Ks[krow][kcol], &kv0, 16);
    __builtin_memcpy(&Ks[krow + 32][kcol], &kv1, 16);
    {
      union { uint4 u; u16 s[8]; } a, b2;
      a.u = vv0; b2.u = vv1;
#pragma unroll
      for (int j = 0; j < 8; j++) {
        Vt[vdg * 8 + j][vkey] = a.s[j];
        Vt[vdg * 8 + j][vkey + 32] = b2.s[j];
      }
    }
    __syncthreads();
    if (kt + 1 < t1) {
      const size_t koff = (size_t)(kt + 1 - t0) * 64 * 768;
      __builtin_memcpy(&kv0, kp + koff, 16);
      __builtin_memcpy(&kv1, kp + koff + (size_t)32 * 768, 16);
      __builtin_memcpy(&vv0, vp + koff, 16);
      __builtin_memcpy(&vv1, vp + koff + (size_t)32 * 768, 16);
    }

    const int kbk = kt * 64;
    {
      f32x4 s4[4] = {};
#pragma unroll
      for (int kg = 0; kg < 2; kg++) {
#pragma unroll
        for (int cc = 0; cc < 4; cc++) {
          bfrag bk = ldfrag(&Ks[cc * 16 + lr][kg * 32 + lq * 8]);
          s4[cc] = MFMA(aq[kg], bk, s4[cc]);
        }
      }
#pragma unroll
      for (int r = 0; r < 4; r++) {
        const int q = q0 + lq * 4 + r;
        float v[4];
        float mx = NEG_BIG;
#pragma unroll
        for (int cc = 0; cc < 4; cc++) {
          v[cc] = (kbk + cc * 16 + lr > q) ? NEG_BIG : s4[cc][r];
          mx = fmaxf(mx, v[cc]);
        }
#pragma unroll
        for (int off = 8; off >= 1; off >>= 1)
          mx = fmaxf(mx, __shfl_xor(mx, off, 16));
        const float mn = fmaxf(mrow[r], mx);
        const float alpha = __expf(mrow[r] - mn);
        float sm = 0.0f;
        float p[4];
#pragma unroll
        for (int cc = 0; cc < 4; cc++) {
          p[cc] = __expf(v[cc] - mn);
          sm += p[cc];
        }
#pragma unroll
        for (int off = 8; off >= 1; off >>= 1) sm += __shfl_xor(sm, off, 16);
        lrow[r] = lrow[r] * alpha + sm;
        mrow[r] = mn;
#pragma unroll
        for (int dt = 0; dt < 4; dt++) o[dt][r] *= alpha;
#pragma unroll
        for (int cc = 0; cc < 4; cc++)
          Ps[wid][lq * 4 + r][cc * 16 + lr] = f2bf(p[cc]);
      }
      __threadfence_block();
      bfrag pf0 = ldfrag(&Ps[wid][lr][lq * 8]);
      bfrag pf1 = ldfrag(&Ps[wid][lr][32 + lq * 8]);
#pragma unroll
      for (int dt = 0; dt < 4; dt++) {
        bfrag v0 = ldfrag(&Vt[dt * 16 + lr][lq * 8]);
        bfrag v1 = ldfrag(&Vt[dt * 16 + lr][32 + lq * 8]);
        o[dt] = MFMA(pf0, v0, o[dt]);
        o[dt] = MFMA(pf1, v1, o[dt]);
      }
    }
  }

  if (qt < 8) {
    // final: normalize and write bf16
#pragma unroll
    for (int r = 0; r < 4; r++) {
      const float inv = 1.0f / fmaxf(lrow[r], 1e-30f);
      const int q = q0 + lq * 4 + r;
#pragma unroll
      for (int dt = 0; dt < 4; dt++)
        O[base + (size_t)q * 768 + dt * 16 + lr] = f2bf(o[dt][r] * inv);
    }
  } else {
    // partial: slot s = bh*72 + off(qt) + c
    int off = 0;
    for (int j = 8; j < qt; ++j) off += j / 8 + 1;
    const int s = bh * 72 + off + c;
    float* Op = (s < 1536) ? Pn + (size_t)s * 4096
                           : Ph + (size_t)(s - 1536) * 4096;
    float* lmp = Ph + 786432 + (size_t)s * 128;
#pragma unroll
    for (int r = 0; r < 4; r++) {
      const int row = wid * 16 + lq * 4 + r;
#pragma unroll
      for (int dt = 0; dt < 4; dt++)
        Op[(size_t)row * 64 + dt * 16 + lr] = o[dt][r];
      if (lr == 0) { lmp[row] = mrow[r]; lmp[64 + row] = lrow[r]; }
    }
  }
}

// ---------------------------------------------------------------------------
// Merge partials for qt in [8,32): O = sum_c exp(m_c-m_g)*O_c / l_g.
// grid (24, 24): x = qt-8, y = bh. 256 thr: thread t -> row t>>2,
// cols (t&3)*16 .. +16.
// ---------------------------------------------------------------------------
__global__ __launch_bounds__(256) void attn_merge_k(
    const float* __restrict__ Pn, const float* __restrict__ Ph,
    u16* __restrict__ O) {
  const int qt = 8 + blockIdx.x;
  const int bh = blockIdx.y;
  const int b = bh / 12, h = bh % 12;
  const int nc = qt / 8 + 1;
  int off = 0;
  for (int j = 8; j < qt; ++j) off += j / 8 + 1;
  const int s0 = bh * 72 + off;
  const int row = threadIdx.x >> 2;
  const int c0 = (threadIdx.x & 3) * 16;
  const float* lmb = Ph + 786432;

  float mg = NEG_BIG;
  for (int cc = 0; cc < nc; ++cc)
    mg = fmaxf(mg, lmb[(size_t)(s0 + cc) * 128 + row]);

  float acc[16];
#pragma unroll
  for (int j = 0; j < 16; j++) acc[j] = 0.0f;
  float lg = 0.0f;
  for (int cc = 0; cc < nc; ++cc) {
    const int s = s0 + cc;
    const float mcv = lmb[(size_t)s * 128 + row];
    const float coef = __expf(mcv - mg);
    lg += coef * lmb[(size_t)s * 128 + 64 + row];
    const float* Op = (s < 1536) ? Pn + (size_t)s * 4096
                                 : Ph + (size_t)(s - 1536) * 4096;
    const float* rp = Op + (size_t)row * 64 + c0;
#pragma unroll
    for (int g = 0; g < 4; g++) {
      float4 v;
      __builtin_memcpy(&v, rp + g * 4, 16);
      acc[g * 4 + 0] += coef * v.x;
      acc[g * 4 + 1] += coef * v.y;
      acc[g * 4 + 2] += coef * v.z;
      acc[g * 4 + 3] += coef * v.w;
    }
  }
  const float inv = 1.0f / fmaxf(lg, 1e-30f);
  const int q = qt * 64 + row;
  const size_t ob = (size_t)b * 2048 * 768 + h * 64 + (size_t)q * 768 + c0;
#pragma unroll
  for (int j = 0; j < 16; j++) O[ob + j] = f2bf(acc[j] * inv);
}

// ---------------------------------------------------------------------------
extern "C" void kernel_launch(void* const* d_in, const int* in_sizes, int n_in,
                              void* d_out, int out_size, void* d_ws,
                              size_t ws_size, hipStream_t stream) {
  (void)in_sizes; (void)n_in; (void)out_size; (void)ws_size;
  const float* x = (const float*)d_in[0];
  const void* mask = d_in[2];

  char* ws = (char*)d_ws;
  u16* Wb  = (u16*)(ws);                        // bf16 arena, 23599104 B
  u16* n1h = (u16*)(ws + 23599104);             // 4096x3072 bf16 (h1 / attn partials)
  u16* Qb  = (u16*)(ws + 48764928);             // 4096x768 (later n2)
  u16* Kb2 = (u16*)(ws + 55056384);             // 4096x768
  u16* Vb2 = (u16*)(ws + 61347840);             // 4096x768
  u16* att = (u16*)(ws + 67639296);             // 4096x768 att, later ht (x1536)
  u16* hs  = (u16*)(ws + 80222208);             // 4096x1536 (attn partial spill)
  float* mfl = (float*)(ws + 92805120);         // 768 floats
  float* x1 = (float*)d_out;                    // x / x1 fp32 live in d_out
  float* Pn = (float*)n1h;                      // 1536 partial slots x 4096 f32
  float* Ph = (float*)hs;                       // 192 slots + m/l at +786432 f32

  u16* Wq = Wb + 0,        *Wk = Wb + 589824,   *Wv = Wb + 1179648;
  u16* Wo = Wb + 1769472,  *w1 = Wb + 2359296,  *w1t = Wb + 4718592;
  u16* w1s = Wb + 5898240, *w2 = Wb + 7077888,  *w2t = Wb + 9437184;
  u16* w2s = Wb + 10616832;
  u16* n1w = Wb + 11796480, *n1b = Wb + 11797248;
  u16* n2w = Wb + 11798016, *n2b = Wb + 11798784;

  Segs sg;
  const int srcidx[14] = {3, 4, 5, 6, 7, 9, 11, 8, 10, 12, 13, 14, 15, 16};
  const int offs[14] = {0, 589824, 1179648, 1769472, 2359296, 4718592,
                        5898240, 7077888, 9437184, 10616832,
                        11796480, 11797248, 11798016, 11798784};
  const int ns[14] = {589824, 589824, 589824, 589824, 2359296, 1179648,
                      1179648, 2359296, 1179648, 1179648, 768, 768, 768, 768};
  const int mms[14] = {0, 0, 0, 0, 0, 1, 2, 0, 0, 0, 0, 0, 0, 0};
  for (int i = 0; i < 14; i++) {
    sg.src[i] = d_in[srcidx[i]];
    sg.off[i] = offs[i];
    sg.n[i] = ns[i];
    sg.mmode[i] = mms[i];
  }

  mask_conv_k<<<1, 256, 0, stream>>>(mask, mfl);
  convert_k<<<dim3(2304, 14), 256, 0, stream>>>(sg, Wb, mfl);

  // n1 = mink_norm(x); also seed d_out with x (residual base for Wo atomics)
  mink_norm_k<<<4096, 256, 0, stream>>>(x, mfl, n1w, n1b, n1h, x1);

  // Q,K,V fused (N=2304)
  GArgs qkv;
  qkv.s[0] = {Wq, Qb, 768, 6, 0};
  qkv.s[1] = {Wk, Kb2, 768, 6, 0};
  qkv.s[2] = {Wv, Vb2, 768, 6, 0};
  gemm128_fused<<<dim3(18, 32), 256, 0, stream>>>(n1h, 768, 768, qkv);

  qcorr_k<<<12288, 256, 0, stream>>>(Qb, mfl);

  // flash attention: 80 chunks/bh, partials into Pn/Ph, then merge
  flash_attn_k<<<dim3(80, 24), 256, 0, stream>>>(Qb, Kb2, Vb2, att, Pn, Ph);
  attn_merge_k<<<dim3(24, 24), 256, 0, stream>>>(Pn, Ph, att);

  // x1 = x + att @ Wo^T  (split-K x4 atomic into d_out holding x)
  gemm128_wo_splitk<<<dim3(6, 32, 4), 256, 0, stream>>>(att, Wo, x1);

  // n2 = mink_norm(x1) -> Qb (mask folded into FFN1 weights)
  mink_norm_k<<<4096, 256, 0, stream>>>(x1, mfl, n2w, n2b, Qb, nullptr);

  // FFN1 fused (N=6144): h1 = gelu(n2@w1^T), ht = silu(n2@w1t_m^T),
  // hs = gelu(n2@w1s_m^T)
  GArgs ffn1;
  ffn1.s[0] = {w1, n1h, 3072, 24, 2};
  ffn1.s[1] = {w1t, att, 1536, 12, 3};
  ffn1.s[2] = {w1s, hs, 1536, 12, 2};
  gemm128_fused<<<dim3(48, 32), 256, 0, stream>>>(Qb, 768, 768, ffn1);

  // out = x1 + 0.5*(h1@w2^T + ht@w2_t^T + hs@w2_s^T), split-K x8 atomic
  ffn2_splitk<<<dim3(6, 32, 8), 256, 0, stream>>>(n1h, att, hs, w2, w2t, w2s,
                                                  (float*)d_out);
}

// Round 6
// 431.077 us; speedup vs baseline: 1.1394x; 1.1394x over previous
//
#include <hip/hip_runtime.h>

// LorentzBlock: B=2, L=2048, D=768, H=12, DH=64, DFF=3072
// R16: (a) revert R15's over-split (ffn2 back to x4, Wo back to x2 — x8
// doubled atomic RMW contention, 90->124us regression); (b) counted-vmcnt
// 2-phase pipeline in gemm128_loop (T3+T4): double LDS buffers, raw
// s_barrier, vmcnt(4) in steady state (never 0 in-loop), lgkmcnt(0)+
// sched_barrier before the reuse barrier (rule #18). Removes the per-K-iter
// full vmcnt(0) drain (~600cy exposed latency) in ALL GEMMs.
// Flash-decode KV-split (R13) unchanged.

typedef unsigned short u16;
typedef __bf16 bfrag __attribute__((ext_vector_type(8)));
typedef float f32x4 __attribute__((ext_vector_type(4)));

#define MFMA(a, b, c) __builtin_amdgcn_mfma_f32_16x16x32_bf16(a, b, c, 0, 0, 0)
#define NEG_BIG (-30000.0f)
#define ASYNC16(g, l)                                                        \
  __builtin_amdgcn_global_load_lds(                                          \
      (const __attribute__((address_space(1))) unsigned int*)(g),            \
      (__attribute__((address_space(3))) unsigned int*)(l), 16, 0, 0)

__device__ __forceinline__ float bf2f(u16 u) {
  unsigned int v = ((unsigned int)u) << 16;
  float f; __builtin_memcpy(&f, &v, 4); return f;
}
__device__ __forceinline__ u16 f2bf(float f) {
  unsigned int v; __builtin_memcpy(&v, &f, 4);
  v += 0x7fffu + ((v >> 16) & 1u);   // RNE
  return (u16)(v >> 16);
}
__device__ __forceinline__ bfrag ldfrag(const u16* p) {
  bfrag v; __builtin_memcpy(&v, p, 16); return v;
}

// ---------------------------------------------------------------------------
// Mask canonicalization -> float[768].
// ---------------------------------------------------------------------------
__global__ __launch_bounds__(256) void mask_conv_k(const void* __restrict__ mask,
                                                   float* __restrict__ mfl) {
  __shared__ int msh;
  if (threadIdx.x == 0) msh = 0;
  __syncthreads();
  const unsigned int* w = (const unsigned int*)mask;
  if (threadIdx.x < 192) {
    const unsigned int v = w[threadIdx.x];
    if ((v & 0xFFFFu) == 0x3F80u) atomicOr(&msh, 4);
    else if (v == 0x3F800000u) atomicOr(&msh, 2);
    else if (v >= 2u) atomicOr(&msh, 1);
  }
  __syncthreads();
  const int m = msh;
  const int mode = (m & 4) ? 3 : (m & 2) ? 2 : (m & 1) ? 1 : 0;
  for (int i = threadIdx.x; i < 768; i += 256) {
    int b;
    if (mode == 3) b = ((const u16*)mask)[i] != 0;
    else if (mode == 2) b = ((const float*)mask)[i] != 0.0f;
    else if (mode == 1) b = ((const unsigned char*)mask)[i] != 0;
    else b = ((const int*)mask)[i] != 0;
    mfl[i] = (float)b;
  }
}

// ---------------------------------------------------------------------------
// Convert fp32 weight segments -> bf16 arena. mmode: 0 none, 1 *m[k],
// 2 *(1-m[k]) with k = i % 768 (mask fold for w1_t / w1_s).
// ---------------------------------------------------------------------------
struct Segs {
  const void* src[14];
  int off[14];
  int n[14];
  int mmode[14];
};

__global__ __launch_bounds__(256) void convert_k(Segs segs, u16* __restrict__ dstb,
                                                 const float* __restrict__ mfl) {
  const int seg = blockIdx.y;
  const int n = segs.n[seg];
  const int mm = segs.mmode[seg];
  u16* dst = dstb + segs.off[seg];
  const float* src = (const float*)segs.src[seg];
  for (int i = (blockIdx.x * 256 + threadIdx.x) * 4; i < n; i += gridDim.x * 1024) {
    float4 v;
    __builtin_memcpy(&v, src + i, 16);
    if (mm) {
      const int k = i % 768;
      float m0 = mfl[k], m1 = mfl[k + 1], m2 = mfl[k + 2], m3 = mfl[k + 3];
      if (mm == 2) { m0 = 1.f - m0; m1 = 1.f - m1; m2 = 1.f - m2; m3 = 1.f - m3; }
      v.x *= m0; v.y *= m1; v.z *= m2; v.w *= m3;
    }
    dst[i] = f2bf(v.x); dst[i + 1] = f2bf(v.y);
    dst[i + 2] = f2bf(v.z); dst[i + 3] = f2bf(v.w);
  }
}

// ---------------------------------------------------------------------------
// Minkowski LayerNorm. fp32 input, bf16 output. Optionally copies the raw
// input row to Xcopy (fp32) -- seeds d_out with x for the Wo split-K atomics.
// ---------------------------------------------------------------------------
__global__ __launch_bounds__(256) void mink_norm_k(
    const float* __restrict__ X, const float* __restrict__ mf,
    const u16* __restrict__ w, const u16* __restrict__ bias,
    u16* __restrict__ Y, float* __restrict__ Xcopy) {
  __shared__ float red[8];
  const int row = blockIdx.x, tid = threadIdx.x;
  const int wid = tid >> 6, lane = tid & 63;
  const size_t roff = (size_t)row * 768;

  float xv[3], mv[3];
  int idx[3];
#pragma unroll
  for (int i = 0; i < 3; i++) {
    idx[i] = tid + i * 256;
    xv[i] = X[roff + idx[i]];
    mv[i] = mf[idx[i]];
  }
  if (Xcopy) {
#pragma unroll
    for (int i = 0; i < 3; i++) Xcopy[roff + idx[i]] = xv[i];
  }
  float s = xv[0] + xv[1] + xv[2];
#pragma unroll
  for (int o = 32; o >= 1; o >>= 1) s += __shfl_xor(s, o, 64);
  if (lane == 0) red[wid] = s;
  __syncthreads();
  const float mean = (red[0] + red[1] + red[2] + red[3]) * (1.0f / 768.0f);
  __syncthreads();

  float xc[3], ss = 0.0f, sm = 0.0f;
#pragma unroll
  for (int i = 0; i < 3; i++) {
    xc[i] = xv[i] - mean;
    ss += xc[i] * xc[i];
    sm += xc[i] * xc[i] * mv[i];
  }
#pragma unroll
  for (int o = 32; o >= 1; o >>= 1) {
    ss += __shfl_xor(ss, o, 64);
    sm += __shfl_xor(sm, o, 64);
  }
  if (lane == 0) { red[wid] = ss; red[4 + wid] = sm; }
  __syncthreads();
  const float sumsq = red[0] + red[1] + red[2] + red[3];
  const float summ = red[4] + red[5] + red[6] + red[7];
  const float var = sumsq * (1.0f / 768.0f);
  const float eta = sumsq - 2.0f * summ;
  const float rs = 1.0f / sqrtf(var + 1e-5f);
  const float re = 1.0f / sqrtf(fabsf(eta) + 1e-5f);

#pragma unroll
  for (int i = 0; i < 3; i++) {
    const float xn = xc[i] * 0.5f * (rs + re);
    Y[roff + idx[i]] = f2bf(bf2f(w[idx[i]]) * xn + bf2f(bias[idx[i]]));
  }
}

// ---------------------------------------------------------------------------
// Q Lorentz correction, in place. 4 rows per block (one per wave).
// ---------------------------------------------------------------------------
__global__ __launch_bounds__(256) void qcorr_k(u16* __restrict__ Q,
                                               const float* __restrict__ mf) {
  const int idx = blockIdx.x * 4 + (threadIdx.x >> 6);  // (b*2048+l)*12+h
  const int t = threadIdx.x & 63;
  const int h = idx % 12;
  const int bl = idx / 12;
  const size_t off = (size_t)bl * 768 + h * 64 + t;
  const float q = bf2f(Q[off]);
  const float m = mf[h * 64 + t];
  float q2 = q * q, qm2 = q * q * m;
#pragma unroll
  for (int o = 32; o >= 1; o >>= 1) {
    q2 += __shfl_xor(q2, o, 64);
    qm2 += __shfl_xor(qm2, o, 64);
  }
  const float qn = sqrtf(q2), qtn = sqrtf(qm2);
  const float sf = (qtn > 1e-6f) ? qn / fmaxf(qtn, 1e-8f) : 0.0f;
  Q[off] = f2bf(q * (1.0f - 0.5f * sf * m) * 0.125f);
}

// ---------------------------------------------------------------------------
// 128x128 MFMA GEMM core, R16: counted-vmcnt 2-phase double-buffered.
// As/Bs are [256][32]: buffer d = rows [d*128, d*128+128). Per K-iter:
//   STAGE(tile t+1 -> buf^1)          (8 loads in flight)
//   vmcnt(4)                          (tile t landed; t+1 stays in flight)
//   raw s_barrier                     (all waves see buf[cur] complete)
//   ds_read buf[cur] + 16 MFMA
//   lgkmcnt(0) + sched_barrier(0)     (reads done, rule #18 anti-hoist)
//   raw s_barrier                     (buf[cur] safe to overwrite at t+2)
// Never drains vmcnt to 0 inside the loop (T4).
// ---------------------------------------------------------------------------
__device__ __forceinline__ void gemm128_loop(
    const u16* __restrict__ Ab, const u16* __restrict__ Wb2,
    int K, int lda, int ldb, u16 (*As)[32], u16 (*Bs)[32], f32x4 acc[4][4]) {
  const int tid = threadIdx.x;
  const int wid = tid >> 6, lane = tid & 63;
  const int lr = lane & 15, lq = lane >> 4;
  const int srow = wid * 32 + (lane >> 2);
  const int scol = (lane & 3) * 8;
  const u16* ga0 = Ab + (size_t)srow * lda + scol;
  const u16* ga1 = Ab + (size_t)(srow + 16) * lda + scol;
  const u16* gb0 = Wb2 + (size_t)srow * ldb + scol;
  const u16* gb1 = Wb2 + (size_t)(srow + 16) * ldb + scol;
  const int wr = (wid >> 1) * 64, wc = (wid & 1) * 64;
  const int nt = K >> 5;

#define STAGE16(dbuf, k0)                                                    \
  {                                                                          \
    u16* _a0 = &As[(dbuf) * 128 + wid * 32][0];                              \
    u16* _a1 = &As[(dbuf) * 128 + wid * 32 + 16][0];                         \
    u16* _b0 = &Bs[(dbuf) * 128 + wid * 32][0];                              \
    u16* _b1 = &Bs[(dbuf) * 128 + wid * 32 + 16][0];                         \
    ASYNC16(ga0 + (k0), _a0);                                                \
    ASYNC16(ga1 + (k0), _a1);                                                \
    ASYNC16(gb0 + (k0), _b0);                                                \
    ASYNC16(gb1 + (k0), _b1);                                                \
  }

  STAGE16(0, 0);
  for (int t = 0; t < nt; ++t) {
    const int cur = t & 1;
    if (t + 1 < nt) {
      STAGE16(cur ^ 1, (t + 1) << 5);
      __builtin_amdgcn_sched_barrier(0);
      asm volatile("s_waitcnt vmcnt(4)" ::: "memory");
    } else {
      asm volatile("s_waitcnt vmcnt(0)" ::: "memory");
    }
    __builtin_amdgcn_s_barrier();
    __builtin_amdgcn_sched_barrier(0);
    bfrag af[4], bf4[4];
#pragma unroll
    for (int i = 0; i < 4; i++)
      af[i] = ldfrag(&As[cur * 128 + wr + i * 16 + lr][lq * 8]);
#pragma unroll
    for (int j = 0; j < 4; j++)
      bf4[j] = ldfrag(&Bs[cur * 128 + wc + j * 16 + lr][lq * 8]);
#pragma unroll
    for (int i = 0; i < 4; i++)
#pragma unroll
      for (int j = 0; j < 4; j++)
        acc[i][j] = MFMA(af[i], bf4[j], acc[i][j]);
    asm volatile("s_waitcnt lgkmcnt(0)" ::: "memory");
    __builtin_amdgcn_sched_barrier(0);
    __builtin_amdgcn_s_barrier();
  }
#undef STAGE16
}

// ---------------------------------------------------------------------------
// Fused multi-segment GEMM, bf16 out: C_seg = epi(A @ Wseg^T).
// Segments partition blockIdx.x. epi: 0 none, 2 gelu(exact), 3 silu.
// ---------------------------------------------------------------------------
struct GSeg { const u16* W; u16* C; int ldc; int nblk; int epi; };
struct GArgs { GSeg s[3]; };

__global__ __launch_bounds__(256) void gemm128_fused(
    const u16* __restrict__ A, int lda, int K, GArgs args) {
  __shared__ __align__(16) u16 As[256][32];
  __shared__ __align__(16) u16 Bs[256][32];
  int cb = blockIdx.x, seg = 0;
  while (cb >= args.s[seg].nblk) { cb -= args.s[seg].nblk; seg++; }
  const GSeg g = args.s[seg];
  const int rowb = blockIdx.y * 128, colb = cb * 128;
  f32x4 acc[4][4] = {};
  gemm128_loop(A + (size_t)rowb * lda, g.W + (size_t)colb * K, K, lda, K,
               As, Bs, acc);

  const int lane = threadIdx.x & 63, wid = threadIdx.x >> 6;
  const int lr = lane & 15, lq = lane >> 4;
  const int wr = (wid >> 1) * 64, wc = (wid & 1) * 64;
#pragma unroll
  for (int i = 0; i < 4; i++)
#pragma unroll
    for (int j = 0; j < 4; j++)
#pragma unroll
      for (int r = 0; r < 4; r++) {
        const int row = rowb + wr + i * 16 + lq * 4 + r;
        const int col = colb + wc + j * 16 + lr;
        float v = acc[i][j][r];
        if (g.epi == 2) v = 0.5f * v * (1.0f + erff(v * 0.70710678118654752f));
        else if (g.epi == 3) v = v / (1.0f + __expf(-v));
        g.C[(size_t)row * g.ldc + col] = f2bf(v);
      }
}

// ---------------------------------------------------------------------------
// Wo projection split-K x2: Out += att @ Wo^T partial. Out (d_out) holds x
// (seeded by mink_norm#1). blockIdx.z selects K-half (K=384 each).
// ---------------------------------------------------------------------------
__global__ __launch_bounds__(256) void gemm128_wo_splitk(
    const u16* __restrict__ A, const u16* __restrict__ W,
    float* __restrict__ Out) {
  __shared__ __align__(16) u16 As[256][32];
  __shared__ __align__(16) u16 Bs[256][32];
  const int rowb = blockIdx.y * 128, colb = blockIdx.x * 128;
  const int z = blockIdx.z;
  f32x4 acc[4][4] = {};
  gemm128_loop(A + (size_t)rowb * 768 + z * 384,
               W + (size_t)colb * 768 + z * 384, 384, 768, 768, As, Bs, acc);

  const int lane = threadIdx.x & 63, wid = threadIdx.x >> 6;
  const int lr = lane & 15, lq = lane >> 4;
  const int wr = (wid >> 1) * 64, wc = (wid & 1) * 64;
#pragma unroll
  for (int i = 0; i < 4; i++)
#pragma unroll
    for (int j = 0; j < 4; j++)
#pragma unroll
      for (int r = 0; r < 4; r++) {
        const int row = rowb + wr + i * 16 + lq * 4 + r;
        const int col = colb + wc + j * 16 + lr;
        atomicAdd(&Out[(size_t)row * 768 + col], acc[i][j][r]);
      }
}

// ---------------------------------------------------------------------------
// FFN2 split-K x4 (R14 config): Out += 0.5 * partial. Out holds x1.
//   z=0: h1[:,0:1536)    @ w2[:,0:1536)^T
//   z=1: h1[:,1536:3072) @ w2[:,1536:3072)^T
//   z=2: ht @ w2t^T   (K=1536)
//   z=3: hs @ w2s^T   (K=1536)
// ---------------------------------------------------------------------------
__global__ __launch_bounds__(256) void ffn2_splitk(
    const u16* __restrict__ H1, const u16* __restrict__ Ht,
    const u16* __restrict__ Hs, const u16* __restrict__ W2,
    const u16* __restrict__ W2t, const u16* __restrict__ W2s,
    float* __restrict__ Out) {
  __shared__ __align__(16) u16 As[256][32];
  __shared__ __align__(16) u16 Bs[256][32];
  const int rowb = blockIdx.y * 128, colb = blockIdx.x * 128;
  const int z = blockIdx.z;
  f32x4 acc[4][4] = {};
  if (z == 0)
    gemm128_loop(H1 + (size_t)rowb * 3072, W2 + (size_t)colb * 3072,
                 1536, 3072, 3072, As, Bs, acc);
  else if (z == 1)
    gemm128_loop(H1 + (size_t)rowb * 3072 + 1536,
                 W2 + (size_t)colb * 3072 + 1536,
                 1536, 3072, 3072, As, Bs, acc);
  else if (z == 2)
    gemm128_loop(Ht + (size_t)rowb * 1536, W2t + (size_t)colb * 1536,
                 1536, 1536, 1536, As, Bs, acc);
  else
    gemm128_loop(Hs + (size_t)rowb * 1536, W2s + (size_t)colb * 1536,
                 1536, 1536, 1536, As, Bs, acc);

  const int lane = threadIdx.x & 63, wid = threadIdx.x >> 6;
  const int lr = lane & 15, lq = lane >> 4;
  const int wr = (wid >> 1) * 64, wc = (wid & 1) * 64;
#pragma unroll
  for (int i = 0; i < 4; i++)
#pragma unroll
    for (int j = 0; j < 4; j++)
#pragma unroll
      for (int r = 0; r < 4; r++) {
        const int row = rowb + wr + i * 16 + lq * 4 + r;
        const int col = colb + wc + j * 16 + lr;
        atomicAdd(&Out[(size_t)row * 768 + col], 0.5f * acc[i][j][r]);
      }
}

// ---------------------------------------------------------------------------
// Flash attention producer, causal, KV-split (R13, unchanged). QBLK=64,
// 4 waves. Per bh: 80 chunks; qt<8 writes final; else (O,m,l) partial.
// ---------------------------------------------------------------------------
__global__ __launch_bounds__(256) void flash_attn_k(
    const u16* __restrict__ Qc, const u16* __restrict__ Kb,
    const u16* __restrict__ Vb, u16* __restrict__ O,
    float* __restrict__ Pn, float* __restrict__ Ph) {
  __shared__ __align__(16) u16 Ks[64][40];
  __shared__ __align__(16) u16 Vt[64][72];
  __shared__ __align__(16) u16 Ps[4][16][72];
  const int tid = threadIdx.x, wid = tid >> 6, lane = tid & 63;
  const int lr = lane & 15, lq = lane >> 4;

  // decode blockIdx.x -> (qt, c); qt descending so long chunks launch first
  int bx = blockIdx.x, qt = 0, c = 0;
  for (int q = 31; q >= 0; --q) {
    const int nc = (q < 8) ? 1 : (q / 8 + 1);
    if (bx < nc) { qt = q; c = bx; break; }
    bx -= nc;
  }
  const int nt = qt + 1;
  const int t0 = c * 8;
  const int t1 = (t0 + 8 < nt) ? t0 + 8 : nt;

  const int qb = qt * 64;
  const int bh = blockIdx.y;
  const int b = bh / 12, h = bh % 12;
  const int q0 = qb + wid * 16;
  const size_t base = (size_t)b * 2048 * 768 + h * 64;

  bfrag aq[2];
  aq[0] = ldfrag(Qc + base + (size_t)(q0 + lr) * 768 + lq * 8);
  aq[1] = ldfrag(Qc + base + (size_t)(q0 + lr) * 768 + 32 + lq * 8);

  f32x4 o[4] = {};
  float mrow[4] = {NEG_BIG, NEG_BIG, NEG_BIG, NEG_BIG};
  float lrow[4] = {0.0f, 0.0f, 0.0f, 0.0f};

  const int krow = tid >> 3;        // 0..31
  const int kcol = (tid & 7) * 8;
  const int vkey = tid & 31;
  const int vdg = tid >> 5;         // 0..7

  const u16* kp = Kb + base + (size_t)(t0 * 64 + krow) * 768 + kcol;
  const u16* vp = Vb + base + (size_t)(t0 * 64 + vkey) * 768 + vdg * 8;

  uint4 kv0, kv1, vv0, vv1;
  __builtin_memcpy(&kv0, kp, 16);
  __builtin_memcpy(&kv1, kp + (size_t)32 * 768, 16);
  __builtin_memcpy(&vv0, vp, 16);
  __builtin_memcpy(&vv1, vp + (size_t)32 * 768, 16);

  for (int kt = t0; kt < t1; kt++) {
    __syncthreads();
    __builtin_memcpy(&Ks[krow][kcol], &kv0, 16);
    __builtin_memcpy(&Ks[krow + 32][kcol], &kv1, 16);
    {
      union { uint4 u; u16 s[8]; } a, b2;
      a.u = vv0; b2.u = vv1;
#pragma unroll
      for (int j = 0; j < 8; j++) {
        Vt[vdg * 8 + j][vkey] = a.s[j];
        Vt[vdg * 8 + j][vkey + 32] = b2.s[j];
      }
    }
    __syncthreads();
    if (kt + 1 < t1) {
      const size_t koff = (size_t)(kt + 1 - t0) * 64 * 768;
      __builtin_memcpy(&kv0, kp + koff, 16);
      __builtin_memcpy(&kv1, kp + koff + (size_t)32 * 768, 16);
      __builtin_memcpy(&vv0, vp + koff, 16);
      __builtin_memcpy(&vv1, vp + koff + (size_t)32 * 768, 16);
    }

    const int kbk = kt * 64;
    {
      f32x4 s4[4] = {};
#pragma unroll
      for (int kg = 0; kg < 2; kg++) {
#pragma unroll
        for (int cc = 0; cc < 4; cc++) {
          bfrag bk = ldfrag(&Ks[cc * 16 + lr][kg * 32 + lq * 8]);
          s4[cc] = MFMA(aq[kg], bk, s4[cc]);
        }
      }
#pragma unroll
      for (int r = 0; r < 4; r++) {
        const int q = q0 + lq * 4 + r;
        float v[4];
        float mx = NEG_BIG;
#pragma unroll
        for (int cc = 0; cc < 4; cc++) {
          v[cc] = (kbk + cc * 16 + lr > q) ? NEG_BIG : s4[cc][r];
          mx = fmaxf(mx, v[cc]);
        }
#pragma unroll
        for (int off = 8; off >= 1; off >>= 1)
          mx = fmaxf(mx, __shfl_xor(mx, off, 16));
        const float mn = fmaxf(mrow[r], mx);
        const float alpha = __expf(mrow[r] - mn);
        float sm = 0.0f;
        float p[4];
#pragma unroll
        for (int cc = 0; cc < 4; cc++) {
          p[cc] = __expf(v[cc] - mn);
          sm += p[cc];
        }
#pragma unroll
        for (int off = 8; off >= 1; off >>= 1) sm += __shfl_xor(sm, off, 16);
        lrow[r] = lrow[r] * alpha + sm;
        mrow[r] = mn;
#pragma unroll
        for (int dt = 0; dt < 4; dt++) o[dt][r] *= alpha;
#pragma unroll
        for (int cc = 0; cc < 4; cc++)
          Ps[wid][lq * 4 + r][cc * 16 + lr] = f2bf(p[cc]);
      }
      __threadfence_block();
      bfrag pf0 = ldfrag(&Ps[wid][lr][lq * 8]);
      bfrag pf1 = ldfrag(&Ps[wid][lr][32 + lq * 8]);
#pragma unroll
      for (int dt = 0; dt < 4; dt++) {
        bfrag v0 = ldfrag(&Vt[dt * 16 + lr][lq * 8]);
        bfrag v1 = ldfrag(&Vt[dt * 16 + lr][32 + lq * 8]);
        o[dt] = MFMA(pf0, v0, o[dt]);
        o[dt] = MFMA(pf1, v1, o[dt]);
      }
    }
  }

  if (qt < 8) {
    // final: normalize and write bf16
#pragma unroll
    for (int r = 0; r < 4; r++) {
      const float inv = 1.0f / fmaxf(lrow[r], 1e-30f);
      const int q = q0 + lq * 4 + r;
#pragma unroll
      for (int dt = 0; dt < 4; dt++)
        O[base + (size_t)q * 768 + dt * 16 + lr] = f2bf(o[dt][r] * inv);
    }
  } else {
    // partial: slot s = bh*72 + off(qt) + c
    int off = 0;
    for (int j = 8; j < qt; ++j) off += j / 8 + 1;
    const int s = bh * 72 + off + c;
    float* Op = (s < 1536) ? Pn + (size_t)s * 4096
                           : Ph + (size_t)(s - 1536) * 4096;
    float* lmp = Ph + 786432 + (size_t)s * 128;
#pragma unroll
    for (int r = 0; r < 4; r++) {
      const int row = wid * 16 + lq * 4 + r;
#pragma unroll
      for (int dt = 0; dt < 4; dt++)
        Op[(size_t)row * 64 + dt * 16 + lr] = o[dt][r];
      if (lr == 0) { lmp[row] = mrow[r]; lmp[64 + row] = lrow[r]; }
    }
  }
}

// ---------------------------------------------------------------------------
// Merge partials for qt in [8,32): O = sum_c exp(m_c-m_g)*O_c / l_g.
// grid (24, 24): x = qt-8, y = bh.
// ---------------------------------------------------------------------------
__global__ __launch_bounds__(256) void attn_merge_k(
    const float* __restrict__ Pn, const float* __restrict__ Ph,
    u16* __restrict__ O) {
  const int qt = 8 + blockIdx.x;
  const int bh = blockIdx.y;
  const int b = bh / 12, h = bh % 12;
  const int nc = qt / 8 + 1;
  int off = 0;
  for (int j = 8; j < qt; ++j) off += j / 8 + 1;
  const int s0 = bh * 72 + off;
  const int row = threadIdx.x >> 2;
  const int c0 = (threadIdx.x & 3) * 16;
  const float* lmb = Ph + 786432;

  float mg = NEG_BIG;
  for (int cc = 0; cc < nc; ++cc)
    mg = fmaxf(mg, lmb[(size_t)(s0 + cc) * 128 + row]);

  float acc[16];
#pragma unroll
  for (int j = 0; j < 16; j++) acc[j] = 0.0f;
  float lg = 0.0f;
  for (int cc = 0; cc < nc; ++cc) {
    const int s = s0 + cc;
    const float mcv = lmb[(size_t)s * 128 + row];
    const float coef = __expf(mcv - mg);
    lg += coef * lmb[(size_t)s * 128 + 64 + row];
    const float* Op = (s < 1536) ? Pn + (size_t)s * 4096
                                 : Ph + (size_t)(s - 1536) * 4096;
    const float* rp = Op + (size_t)row * 64 + c0;
#pragma unroll
    for (int g = 0; g < 4; g++) {
      float4 v;
      __builtin_memcpy(&v, rp + g * 4, 16);
      acc[g * 4 + 0] += coef * v.x;
      acc[g * 4 + 1] += coef * v.y;
      acc[g * 4 + 2] += coef * v.z;
      acc[g * 4 + 3] += coef * v.w;
    }
  }
  const float inv = 1.0f / fmaxf(lg, 1e-30f);
  const int q = qt * 64 + row;
  const size_t ob = (size_t)b * 2048 * 768 + h * 64 + (size_t)q * 768 + c0;
#pragma unroll
  for (int j = 0; j < 16; j++) O[ob + j] = f2bf(acc[j] * inv);
}

// ---------------------------------------------------------------------------
extern "C" void kernel_launch(void* const* d_in, const int* in_sizes, int n_in,
                              void* d_out, int out_size, void* d_ws,
                              size_t ws_size, hipStream_t stream) {
  (void)in_sizes; (void)n_in; (void)out_size; (void)ws_size;
  const float* x = (const float*)d_in[0];
  const void* mask = d_in[2];

  char* ws = (char*)d_ws;
  u16* Wb  = (u16*)(ws);                        // bf16 arena, 23599104 B
  u16* n1h = (u16*)(ws + 23599104);             // 4096x3072 bf16 (h1 / attn partials)
  u16* Qb  = (u16*)(ws + 48764928);             // 4096x768 (later n2)
  u16* Kb2 = (u16*)(ws + 55056384);             // 4096x768
  u16* Vb2 = (u16*)(ws + 61347840);             // 4096x768
  u16* att = (u16*)(ws + 67639296);             // 4096x768 att, later ht (x1536)
  u16* hs  = (u16*)(ws + 80222208);             // 4096x1536 (attn partial spill)
  float* mfl = (float*)(ws + 92805120);         // 768 floats
  float* x1 = (float*)d_out;                    // x / x1 fp32 live in d_out
  float* Pn = (float*)n1h;                      // 1536 partial slots x 4096 f32
  float* Ph = (float*)hs;                       // 192 slots + m/l at +786432 f32

  u16* Wq = Wb + 0,        *Wk = Wb + 589824,   *Wv = Wb + 1179648;
  u16* Wo = Wb + 1769472,  *w1 = Wb + 2359296,  *w1t = Wb + 4718592;
  u16* w1s = Wb + 5898240, *w2 = Wb + 7077888,  *w2t = Wb + 9437184;
  u16* w2s = Wb + 10616832;
  u16* n1w = Wb + 11796480, *n1b = Wb + 11797248;
  u16* n2w = Wb + 11798016, *n2b = Wb + 11798784;

  Segs sg;
  const int srcidx[14] = {3, 4, 5, 6, 7, 9, 11, 8, 10, 12, 13, 14, 15, 16};
  const int offs[14] = {0, 589824, 1179648, 1769472, 2359296, 4718592,
                        5898240, 7077888, 9437184, 10616832,
                        11796480, 11797248, 11798016, 11798784};
  const int ns[14] = {589824, 589824, 589824, 589824, 2359296, 1179648,
                      1179648, 2359296, 1179648, 1179648, 768, 768, 768, 768};
  const int mms[14] = {0, 0, 0, 0, 0, 1, 2, 0, 0, 0, 0, 0, 0, 0};
  for (int i = 0; i < 14; i++) {
    sg.src[i] = d_in[srcidx[i]];
    sg.off[i] = offs[i];
    sg.n[i] = ns[i];
    sg.mmode[i] = mms[i];
  }

  mask_conv_k<<<1, 256, 0, stream>>>(mask, mfl);
  convert_k<<<dim3(2304, 14), 256, 0, stream>>>(sg, Wb, mfl);

  // n1 = mink_norm(x); also seed d_out with x (residual base for Wo atomics)
  mink_norm_k<<<4096, 256, 0, stream>>>(x, mfl, n1w, n1b, n1h, x1);

  // Q,K,V fused (N=2304)
  GArgs qkv;
  qkv.s[0] = {Wq, Qb, 768, 6, 0};
  qkv.s[1] = {Wk, Kb2, 768, 6, 0};
  qkv.s[2] = {Wv, Vb2, 768, 6, 0};
  gemm128_fused<<<dim3(18, 32), 256, 0, stream>>>(n1h, 768, 768, qkv);

  qcorr_k<<<12288, 256, 0, stream>>>(Qb, mfl);

  // flash attention: 80 chunks/bh, partials into Pn/Ph, then merge
  flash_attn_k<<<dim3(80, 24), 256, 0, stream>>>(Qb, Kb2, Vb2, att, Pn, Ph);
  attn_merge_k<<<dim3(24, 24), 256, 0, stream>>>(Pn, Ph, att);

  // x1 = x + att @ Wo^T  (split-K x2 atomic into d_out holding x)
  gemm128_wo_splitk<<<dim3(6, 32, 2), 256, 0, stream>>>(att, Wo, x1);

  // n2 = mink_norm(x1) -> Qb (mask folded into FFN1 weights)
  mink_norm_k<<<4096, 256, 0, stream>>>(x1, mfl, n2w, n2b, Qb, nullptr);

  // FFN1 fused (N=6144): h1 = gelu(n2@w1^T), ht = silu(n2@w1t_m^T),
  // hs = gelu(n2@w1s_m^T)
  GArgs ffn1;
  ffn1.s[0] = {w1, n1h, 3072, 24, 2};
  ffn1.s[1] = {w1t, att, 1536, 12, 3};
  ffn1.s[2] = {w1s, hs, 1536, 12, 2};
  gemm128_fused<<<dim3(48, 32), 256, 0, stream>>>(Qb, 768, 768, ffn1);

  // out = x1 + 0.5*(h1@w2^T + ht@w2_t^T + hs@w2_s^T), split-K x4 atomic
  ffn2_splitk<<<dim3(6, 32, 4), 256, 0, stream>>>(n1h, att, hs, w2, w2t, w2s,
                                                  (float*)d_out);
}

// Round 7
// 424.166 us; speedup vs baseline: 1.1580x; 1.0163x over previous
//
#include <hip/hip_runtime.h>

// LorentzBlock: B=2, L=2048, D=768, H=12, DH=64, DFF=3072
// R17: XCD-aware work swizzle (T1, chunked/bijective) on all 4 GEMMs.
// R16 post-mortem: ffn2 FETCH=167MB vs ~60MB unique (2.8x over-fetch) --
// the 6 col-blocks sharing each A-row-panel have consecutive linear IDs ->
// scattered over 6 XCDs -> each private L2 fetches the panel separately.
// Remap work so each XCD owns contiguous work IDs (= whole row panels):
// w = (orig%8)*(nwg/8) + orig/8 (all grids %8==0 -> bijective).
// Keeps R16's counted-vmcnt 2-phase gemm128_loop + R13 flash-decode.

typedef unsigned short u16;
typedef __bf16 bfrag __attribute__((ext_vector_type(8)));
typedef float f32x4 __attribute__((ext_vector_type(4)));

#define MFMA(a, b, c) __builtin_amdgcn_mfma_f32_16x16x32_bf16(a, b, c, 0, 0, 0)
#define NEG_BIG (-30000.0f)
#define ASYNC16(g, l)                                                        \
  __builtin_amdgcn_global_load_lds(                                          \
      (const __attribute__((address_space(1))) unsigned int*)(g),            \
      (__attribute__((address_space(3))) unsigned int*)(l), 16, 0, 0)

__device__ __forceinline__ float bf2f(u16 u) {
  unsigned int v = ((unsigned int)u) << 16;
  float f; __builtin_memcpy(&f, &v, 4); return f;
}
__device__ __forceinline__ u16 f2bf(float f) {
  unsigned int v; __builtin_memcpy(&v, &f, 4);
  v += 0x7fffu + ((v >> 16) & 1u);   // RNE
  return (u16)(v >> 16);
}
__device__ __forceinline__ bfrag ldfrag(const u16* p) {
  bfrag v; __builtin_memcpy(&v, p, 16); return v;
}

// XCD-chunked bijective swizzle of the linear workgroup id. Requires
// nwg % 8 == 0 (all call sites comply); identity fallback otherwise.
__device__ __forceinline__ int xcd_work_id() {
  const int nx = gridDim.x, ny = gridDim.y;
  const int nwg = nx * ny * gridDim.z;
  const int orig = blockIdx.x + nx * (blockIdx.y + ny * blockIdx.z);
  if (nwg & 7) return orig;
  return (orig & 7) * (nwg >> 3) + (orig >> 3);
}

// ---------------------------------------------------------------------------
// Mask canonicalization -> float[768].
// ---------------------------------------------------------------------------
__global__ __launch_bounds__(256) void mask_conv_k(const void* __restrict__ mask,
                                                   float* __restrict__ mfl) {
  __shared__ int msh;
  if (threadIdx.x == 0) msh = 0;
  __syncthreads();
  const unsigned int* w = (const unsigned int*)mask;
  if (threadIdx.x < 192) {
    const unsigned int v = w[threadIdx.x];
    if ((v & 0xFFFFu) == 0x3F80u) atomicOr(&msh, 4);
    else if (v == 0x3F800000u) atomicOr(&msh, 2);
    else if (v >= 2u) atomicOr(&msh, 1);
  }
  __syncthreads();
  const int m = msh;
  const int mode = (m & 4) ? 3 : (m & 2) ? 2 : (m & 1) ? 1 : 0;
  for (int i = threadIdx.x; i < 768; i += 256) {
    int b;
    if (mode == 3) b = ((const u16*)mask)[i] != 0;
    else if (mode == 2) b = ((const float*)mask)[i] != 0.0f;
    else if (mode == 1) b = ((const unsigned char*)mask)[i] != 0;
    else b = ((const int*)mask)[i] != 0;
    mfl[i] = (float)b;
  }
}

// ---------------------------------------------------------------------------
// Convert fp32 weight segments -> bf16 arena. mmode: 0 none, 1 *m[k],
// 2 *(1-m[k]) with k = i % 768 (mask fold for w1_t / w1_s).
// ---------------------------------------------------------------------------
struct Segs {
  const void* src[14];
  int off[14];
  int n[14];
  int mmode[14];
};

__global__ __launch_bounds__(256) void convert_k(Segs segs, u16* __restrict__ dstb,
                                                 const float* __restrict__ mfl) {
  const int seg = blockIdx.y;
  const int n = segs.n[seg];
  const int mm = segs.mmode[seg];
  u16* dst = dstb + segs.off[seg];
  const float* src = (const float*)segs.src[seg];
  for (int i = (blockIdx.x * 256 + threadIdx.x) * 4; i < n; i += gridDim.x * 1024) {
    float4 v;
    __builtin_memcpy(&v, src + i, 16);
    if (mm) {
      const int k = i % 768;
      float m0 = mfl[k], m1 = mfl[k + 1], m2 = mfl[k + 2], m3 = mfl[k + 3];
      if (mm == 2) { m0 = 1.f - m0; m1 = 1.f - m1; m2 = 1.f - m2; m3 = 1.f - m3; }
      v.x *= m0; v.y *= m1; v.z *= m2; v.w *= m3;
    }
    dst[i] = f2bf(v.x); dst[i + 1] = f2bf(v.y);
    dst[i + 2] = f2bf(v.z); dst[i + 3] = f2bf(v.w);
  }
}

// ---------------------------------------------------------------------------
// Minkowski LayerNorm. fp32 input, bf16 output. Optionally copies the raw
// input row to Xcopy (fp32) -- seeds d_out with x for the Wo split-K atomics.
// ---------------------------------------------------------------------------
__global__ __launch_bounds__(256) void mink_norm_k(
    const float* __restrict__ X, const float* __restrict__ mf,
    const u16* __restrict__ w, const u16* __restrict__ bias,
    u16* __restrict__ Y, float* __restrict__ Xcopy) {
  __shared__ float red[8];
  const int row = blockIdx.x, tid = threadIdx.x;
  const int wid = tid >> 6, lane = tid & 63;
  const size_t roff = (size_t)row * 768;

  float xv[3], mv[3];
  int idx[3];
#pragma unroll
  for (int i = 0; i < 3; i++) {
    idx[i] = tid + i * 256;
    xv[i] = X[roff + idx[i]];
    mv[i] = mf[idx[i]];
  }
  if (Xcopy) {
#pragma unroll
    for (int i = 0; i < 3; i++) Xcopy[roff + idx[i]] = xv[i];
  }
  float s = xv[0] + xv[1] + xv[2];
#pragma unroll
  for (int o = 32; o >= 1; o >>= 1) s += __shfl_xor(s, o, 64);
  if (lane == 0) red[wid] = s;
  __syncthreads();
  const float mean = (red[0] + red[1] + red[2] + red[3]) * (1.0f / 768.0f);
  __syncthreads();

  float xc[3], ss = 0.0f, sm = 0.0f;
#pragma unroll
  for (int i = 0; i < 3; i++) {
    xc[i] = xv[i] - mean;
    ss += xc[i] * xc[i];
    sm += xc[i] * xc[i] * mv[i];
  }
#pragma unroll
  for (int o = 32; o >= 1; o >>= 1) {
    ss += __shfl_xor(ss, o, 64);
    sm += __shfl_xor(sm, o, 64);
  }
  if (lane == 0) { red[wid] = ss; red[4 + wid] = sm; }
  __syncthreads();
  const float sumsq = red[0] + red[1] + red[2] + red[3];
  const float summ = red[4] + red[5] + red[6] + red[7];
  const float var = sumsq * (1.0f / 768.0f);
  const float eta = sumsq - 2.0f * summ;
  const float rs = 1.0f / sqrtf(var + 1e-5f);
  const float re = 1.0f / sqrtf(fabsf(eta) + 1e-5f);

#pragma unroll
  for (int i = 0; i < 3; i++) {
    const float xn = xc[i] * 0.5f * (rs + re);
    Y[roff + idx[i]] = f2bf(bf2f(w[idx[i]]) * xn + bf2f(bias[idx[i]]));
  }
}

// ---------------------------------------------------------------------------
// Q Lorentz correction, in place. 4 rows per block (one per wave).
// ---------------------------------------------------------------------------
__global__ __launch_bounds__(256) void qcorr_k(u16* __restrict__ Q,
                                               const float* __restrict__ mf) {
  const int idx = blockIdx.x * 4 + (threadIdx.x >> 6);  // (b*2048+l)*12+h
  const int t = threadIdx.x & 63;
  const int h = idx % 12;
  const int bl = idx / 12;
  const size_t off = (size_t)bl * 768 + h * 64 + t;
  const float q = bf2f(Q[off]);
  const float m = mf[h * 64 + t];
  float q2 = q * q, qm2 = q * q * m;
#pragma unroll
  for (int o = 32; o >= 1; o >>= 1) {
    q2 += __shfl_xor(q2, o, 64);
    qm2 += __shfl_xor(qm2, o, 64);
  }
  const float qn = sqrtf(q2), qtn = sqrtf(qm2);
  const float sf = (qtn > 1e-6f) ? qn / fmaxf(qtn, 1e-8f) : 0.0f;
  Q[off] = f2bf(q * (1.0f - 0.5f * sf * m) * 0.125f);
}

// ---------------------------------------------------------------------------
// 128x128 MFMA GEMM core, R16: counted-vmcnt 2-phase double-buffered.
// As/Bs are [256][32]: buffer d = rows [d*128, d*128+128). Per K-iter:
//   STAGE(tile t+1 -> buf^1); vmcnt(4); s_barrier; ds_read+MFMA buf[cur];
//   lgkmcnt(0)+sched_barrier; s_barrier. Never vmcnt(0) in-loop (T4).
// ---------------------------------------------------------------------------
__device__ __forceinline__ void gemm128_loop(
    const u16* __restrict__ Ab, const u16* __restrict__ Wb2,
    int K, int lda, int ldb, u16 (*As)[32], u16 (*Bs)[32], f32x4 acc[4][4]) {
  const int tid = threadIdx.x;
  const int wid = tid >> 6, lane = tid & 63;
  const int lr = lane & 15, lq = lane >> 4;
  const int srow = wid * 32 + (lane >> 2);
  const int scol = (lane & 3) * 8;
  const u16* ga0 = Ab + (size_t)srow * lda + scol;
  const u16* ga1 = Ab + (size_t)(srow + 16) * lda + scol;
  const u16* gb0 = Wb2 + (size_t)srow * ldb + scol;
  const u16* gb1 = Wb2 + (size_t)(srow + 16) * ldb + scol;
  const int wr = (wid >> 1) * 64, wc = (wid & 1) * 64;
  const int nt = K >> 5;

#define STAGE16(dbuf, k0)                                                    \
  {                                                                          \
    u16* _a0 = &As[(dbuf) * 128 + wid * 32][0];                              \
    u16* _a1 = &As[(dbuf) * 128 + wid * 32 + 16][0];                         \
    u16* _b0 = &Bs[(dbuf) * 128 + wid * 32][0];                              \
    u16* _b1 = &Bs[(dbuf) * 128 + wid * 32 + 16][0];                         \
    ASYNC16(ga0 + (k0), _a0);                                                \
    ASYNC16(ga1 + (k0), _a1);                                                \
    ASYNC16(gb0 + (k0), _b0);                                                \
    ASYNC16(gb1 + (k0), _b1);                                                \
  }

  STAGE16(0, 0);
  for (int t = 0; t < nt; ++t) {
    const int cur = t & 1;
    if (t + 1 < nt) {
      STAGE16(cur ^ 1, (t + 1) << 5);
      __builtin_amdgcn_sched_barrier(0);
      asm volatile("s_waitcnt vmcnt(4)" ::: "memory");
    } else {
      asm volatile("s_waitcnt vmcnt(0)" ::: "memory");
    }
    __builtin_amdgcn_s_barrier();
    __builtin_amdgcn_sched_barrier(0);
    bfrag af[4], bf4[4];
#pragma unroll
    for (int i = 0; i < 4; i++)
      af[i] = ldfrag(&As[cur * 128 + wr + i * 16 + lr][lq * 8]);
#pragma unroll
    for (int j = 0; j < 4; j++)
      bf4[j] = ldfrag(&Bs[cur * 128 + wc + j * 16 + lr][lq * 8]);
#pragma unroll
    for (int i = 0; i < 4; i++)
#pragma unroll
      for (int j = 0; j < 4; j++)
        acc[i][j] = MFMA(af[i], bf4[j], acc[i][j]);
    asm volatile("s_waitcnt lgkmcnt(0)" ::: "memory");
    __builtin_amdgcn_sched_barrier(0);
    __builtin_amdgcn_s_barrier();
  }
#undef STAGE16
}

// ---------------------------------------------------------------------------
// Fused multi-segment GEMM, bf16 out: C_seg = epi(A @ Wseg^T).
// Work id XCD-swizzled; column index fastest so same-row-panel blocks
// (sharing the A panel) land on one XCD.
// ---------------------------------------------------------------------------
struct GSeg { const u16* W; u16* C; int ldc; int nblk; int epi; };
struct GArgs { GSeg s[3]; };

__global__ __launch_bounds__(256) void gemm128_fused(
    const u16* __restrict__ A, int lda, int K, GArgs args) {
  __shared__ __align__(16) u16 As[256][32];
  __shared__ __align__(16) u16 Bs[256][32];
  const int w = xcd_work_id();
  int cb = w % gridDim.x, seg = 0;
  const int by = w / gridDim.x;
  while (cb >= args.s[seg].nblk) { cb -= args.s[seg].nblk; seg++; }
  const GSeg g = args.s[seg];
  const int rowb = by * 128, colb = cb * 128;
  f32x4 acc[4][4] = {};
  gemm128_loop(A + (size_t)rowb * lda, g.W + (size_t)colb * K, K, lda, K,
               As, Bs, acc);

  const int lane = threadIdx.x & 63, wid = threadIdx.x >> 6;
  const int lr = lane & 15, lq = lane >> 4;
  const int wr = (wid >> 1) * 64, wc = (wid & 1) * 64;
#pragma unroll
  for (int i = 0; i < 4; i++)
#pragma unroll
    for (int j = 0; j < 4; j++)
#pragma unroll
      for (int r = 0; r < 4; r++) {
        const int row = rowb + wr + i * 16 + lq * 4 + r;
        const int col = colb + wc + j * 16 + lr;
        float v = acc[i][j][r];
        if (g.epi == 2) v = 0.5f * v * (1.0f + erff(v * 0.70710678118654752f));
        else if (g.epi == 3) v = v / (1.0f + __expf(-v));
        g.C[(size_t)row * g.ldc + col] = f2bf(v);
      }
}

// ---------------------------------------------------------------------------
// Wo projection split-K x2: Out += att @ Wo^T partial. Out (d_out) holds x.
// XCD-swizzled work id; (col, z) fastest so same-row blocks colocate.
// ---------------------------------------------------------------------------
__global__ __launch_bounds__(256) void gemm128_wo_splitk(
    const u16* __restrict__ A, const u16* __restrict__ W,
    float* __restrict__ Out) {
  __shared__ __align__(16) u16 As[256][32];
  __shared__ __align__(16) u16 Bs[256][32];
  const int w = xcd_work_id();
  const int bx = w % gridDim.x;
  const int by = (w / gridDim.x) % gridDim.y;
  const int z = w / (gridDim.x * gridDim.y);
  const int rowb = by * 128, colb = bx * 128;
  f32x4 acc[4][4] = {};
  gemm128_loop(A + (size_t)rowb * 768 + z * 384,
               W + (size_t)colb * 768 + z * 384, 384, 768, 768, As, Bs, acc);

  const int lane = threadIdx.x & 63, wid = threadIdx.x >> 6;
  const int lr = lane & 15, lq = lane >> 4;
  const int wr = (wid >> 1) * 64, wc = (wid & 1) * 64;
#pragma unroll
  for (int i = 0; i < 4; i++)
#pragma unroll
    for (int j = 0; j < 4; j++)
#pragma unroll
      for (int r = 0; r < 4; r++) {
        const int row = rowb + wr + i * 16 + lq * 4 + r;
        const int col = colb + wc + j * 16 + lr;
        atomicAdd(&Out[(size_t)row * 768 + col], acc[i][j][r]);
      }
}

// ---------------------------------------------------------------------------
// FFN2 split-K x4: Out += 0.5 * partial. Out holds x1. XCD-swizzled:
// work id (x fastest, then y, then z) -> each XCD owns contiguous
// (y,z)-panels, so the 6 col-blocks sharing an A panel share one L2.
// ---------------------------------------------------------------------------
__global__ __launch_bounds__(256) void ffn2_splitk(
    const u16* __restrict__ H1, const u16* __restrict__ Ht,
    const u16* __restrict__ Hs, const u16* __restrict__ W2,
    const u16* __restrict__ W2t, const u16* __restrict__ W2s,
    float* __restrict__ Out) {
  __shared__ __align__(16) u16 As[256][32];
  __shared__ __align__(16) u16 Bs[256][32];
  const int w = xcd_work_id();
  const int bx = w % gridDim.x;
  const int by = (w / gridDim.x) % gridDim.y;
  const int z = w / (gridDim.x * gridDim.y);
  const int rowb = by * 128, colb = bx * 128;
  f32x4 acc[4][4] = {};
  if (z == 0)
    gemm128_loop(H1 + (size_t)rowb * 3072, W2 + (size_t)colb * 3072,
                 1536, 3072, 3072, As, Bs, acc);
  else if (z == 1)
    gemm128_loop(H1 + (size_t)rowb * 3072 + 1536,
                 W2 + (size_t)colb * 3072 + 1536,
                 1536, 3072, 3072, As, Bs, acc);
  else if (z == 2)
    gemm128_loop(Ht + (size_t)rowb * 1536, W2t + (size_t)colb * 1536,
                 1536, 1536, 1536, As, Bs, acc);
  else
    gemm128_loop(Hs + (size_t)rowb * 1536, W2s + (size_t)colb * 1536,
                 1536, 1536, 1536, As, Bs, acc);

  const int lane = threadIdx.x & 63, wid = threadIdx.x >> 6;
  const int lr = lane & 15, lq = lane >> 4;
  const int wr = (wid >> 1) * 64, wc = (wid & 1) * 64;
#pragma unroll
  for (int i = 0; i < 4; i++)
#pragma unroll
    for (int j = 0; j < 4; j++)
#pragma unroll
      for (int r = 0; r < 4; r++) {
        const int row = rowb + wr + i * 16 + lq * 4 + r;
        const int col = colb + wc + j * 16 + lr;
        atomicAdd(&Out[(size_t)row * 768 + col], 0.5f * acc[i][j][r]);
      }
}

// ---------------------------------------------------------------------------
// Flash attention producer, causal, KV-split (R13, unchanged). QBLK=64,
// 4 waves. Per bh: 80 chunks; qt<8 writes final; else (O,m,l) partial.
// ---------------------------------------------------------------------------
__global__ __launch_bounds__(256) void flash_attn_k(
    const u16* __restrict__ Qc, const u16* __restrict__ Kb,
    const u16* __restrict__ Vb, u16* __restrict__ O,
    float* __restrict__ Pn, float* __restrict__ Ph) {
  __shared__ __align__(16) u16 Ks[64][40];
  __shared__ __align__(16) u16 Vt[64][72];
  __shared__ __align__(16) u16 Ps[4][16][72];
  const int tid = threadIdx.x, wid = tid >> 6, lane = tid & 63;
  const int lr = lane & 15, lq = lane >> 4;

  // decode blockIdx.x -> (qt, c); qt descending so long chunks launch first
  int bx = blockIdx.x, qt = 0, c = 0;
  for (int q = 31; q >= 0; --q) {
    const int nc = (q < 8) ? 1 : (q / 8 + 1);
    if (bx < nc) { qt = q; c = bx; break; }
    bx -= nc;
  }
  const int nt = qt + 1;
  const int t0 = c * 8;
  const int t1 = (t0 + 8 < nt) ? t0 + 8 : nt;

  const int qb = qt * 64;
  const int bh = blockIdx.y;
  const int b = bh / 12, h = bh % 12;
  const int q0 = qb + wid * 16;
  const size_t base = (size_t)b * 2048 * 768 + h * 64;

  bfrag aq[2];
  aq[0] = ldfrag(Qc + base + (size_t)(q0 + lr) * 768 + lq * 8);
  aq[1] = ldfrag(Qc + base + (size_t)(q0 + lr) * 768 + 32 + lq * 8);

  f32x4 o[4] = {};
  float mrow[4] = {NEG_BIG, NEG_BIG, NEG_BIG, NEG_BIG};
  float lrow[4] = {0.0f, 0.0f, 0.0f, 0.0f};

  const int krow = tid >> 3;        // 0..31
  const int kcol = (tid & 7) * 8;
  const int vkey = tid & 31;
  const int vdg = tid >> 5;         // 0..7

  const u16* kp = Kb + base + (size_t)(t0 * 64 + krow) * 768 + kcol;
  const u16* vp = Vb + base + (size_t)(t0 * 64 + vkey) * 768 + vdg * 8;

  uint4 kv0, kv1, vv0, vv1;
  __builtin_memcpy(&kv0, kp, 16);
  __builtin_memcpy(&kv1, kp + (size_t)32 * 768, 16);
  __builtin_memcpy(&vv0, vp, 16);
  __builtin_memcpy(&vv1, vp + (size_t)32 * 768, 16);

  for (int kt = t0; kt < t1; kt++) {
    __syncthreads();
    __builtin_memcpy(&Ks[krow][kcol], &kv0, 16);
    __builtin_memcpy(&Ks[krow + 32][kcol], &kv1, 16);
    {
      union { uint4 u; u16 s[8]; } a, b2;
      a.u = vv0; b2.u = vv1;
#pragma unroll
      for (int j = 0; j < 8; j++) {
        Vt[vdg * 8 + j][vkey] = a.s[j];
        Vt[vdg * 8 + j][vkey + 32] = b2.s[j];
      }
    }
    __syncthreads();
    if (kt + 1 < t1) {
      const size_t koff = (size_t)(kt + 1 - t0) * 64 * 768;
      __builtin_memcpy(&kv0, kp + koff, 16);
      __builtin_memcpy(&kv1, kp + koff + (size_t)32 * 768, 16);
      __builtin_memcpy(&vv0, vp + koff, 16);
      __builtin_memcpy(&vv1, vp + koff + (size_t)32 * 768, 16);
    }

    const int kbk = kt * 64;
    {
      f32x4 s4[4] = {};
#pragma unroll
      for (int kg = 0; kg < 2; kg++) {
#pragma unroll
        for (int cc = 0; cc < 4; cc++) {
          bfrag bk = ldfrag(&Ks[cc * 16 + lr][kg * 32 + lq * 8]);
          s4[cc] = MFMA(aq[kg], bk, s4[cc]);
        }
      }
#pragma unroll
      for (int r = 0; r < 4; r++) {
        const int q = q0 + lq * 4 + r;
        float v[4];
        float mx = NEG_BIG;
#pragma unroll
        for (int cc = 0; cc < 4; cc++) {
          v[cc] = (kbk + cc * 16 + lr > q) ? NEG_BIG : s4[cc][r];
          mx = fmaxf(mx, v[cc]);
        }
#pragma unroll
        for (int off = 8; off >= 1; off >>= 1)
          mx = fmaxf(mx, __shfl_xor(mx, off, 16));
        const float mn = fmaxf(mrow[r], mx);
        const float alpha = __expf(mrow[r] - mn);
        float sm = 0.0f;
        float p[4];
#pragma unroll
        for (int cc = 0; cc < 4; cc++) {
          p[cc] = __expf(v[cc] - mn);
          sm += p[cc];
        }
#pragma unroll
        for (int off = 8; off >= 1; off >>= 1) sm += __shfl_xor(sm, off, 16);
        lrow[r] = lrow[r] * alpha + sm;
        mrow[r] = mn;
#pragma unroll
        for (int dt = 0; dt < 4; dt++) o[dt][r] *= alpha;
#pragma unroll
        for (int cc = 0; cc < 4; cc++)
          Ps[wid][lq * 4 + r][cc * 16 + lr] = f2bf(p[cc]);
      }
      __threadfence_block();
      bfrag pf0 = ldfrag(&Ps[wid][lr][lq * 8]);
      bfrag pf1 = ldfrag(&Ps[wid][lr][32 + lq * 8]);
#pragma unroll
      for (int dt = 0; dt < 4; dt++) {
        bfrag v0 = ldfrag(&Vt[dt * 16 + lr][lq * 8]);
        bfrag v1 = ldfrag(&Vt[dt * 16 + lr][32 + lq * 8]);
        o[dt] = MFMA(pf0, v0, o[dt]);
        o[dt] = MFMA(pf1, v1, o[dt]);
      }
    }
  }

  if (qt < 8) {
    // final: normalize and write bf16
#pragma unroll
    for (int r = 0; r < 4; r++) {
      const float inv = 1.0f / fmaxf(lrow[r], 1e-30f);
      const int q = q0 + lq * 4 + r;
#pragma unroll
      for (int dt = 0; dt < 4; dt++)
        O[base + (size_t)q * 768 + dt * 16 + lr] = f2bf(o[dt][r] * inv);
    }
  } else {
    // partial: slot s = bh*72 + off(qt) + c
    int off = 0;
    for (int j = 8; j < qt; ++j) off += j / 8 + 1;
    const int s = bh * 72 + off + c;
    float* Op = (s < 1536) ? Pn + (size_t)s * 4096
                           : Ph + (size_t)(s - 1536) * 4096;
    float* lmp = Ph + 786432 + (size_t)s * 128;
#pragma unroll
    for (int r = 0; r < 4; r++) {
      const int row = wid * 16 + lq * 4 + r;
#pragma unroll
      for (int dt = 0; dt < 4; dt++)
        Op[(size_t)row * 64 + dt * 16 + lr] = o[dt][r];
      if (lr == 0) { lmp[row] = mrow[r]; lmp[64 + row] = lrow[r]; }
    }
  }
}

// ---------------------------------------------------------------------------
// Merge partials for qt in [8,32): O = sum_c exp(m_c-m_g)*O_c / l_g.
// grid (24, 24): x = qt-8, y = bh.
// ---------------------------------------------------------------------------
__global__ __launch_bounds__(256) void attn_merge_k(
    const float* __restrict__ Pn, const float* __restrict__ Ph,
    u16* __restrict__ O) {
  const int qt = 8 + blockIdx.x;
  const int bh = blockIdx.y;
  const int b = bh / 12, h = bh % 12;
  const int nc = qt / 8 + 1;
  int off = 0;
  for (int j = 8; j < qt; ++j) off += j / 8 + 1;
  const int s0 = bh * 72 + off;
  const int row = threadIdx.x >> 2;
  const int c0 = (threadIdx.x & 3) * 16;
  const float* lmb = Ph + 786432;

  float mg = NEG_BIG;
  for (int cc = 0; cc < nc; ++cc)
    mg = fmaxf(mg, lmb[(size_t)(s0 + cc) * 128 + row]);

  float acc[16];
#pragma unroll
  for (int j = 0; j < 16; j++) acc[j] = 0.0f;
  float lg = 0.0f;
  for (int cc = 0; cc < nc; ++cc) {
    const int s = s0 + cc;
    const float mcv = lmb[(size_t)s * 128 + row];
    const float coef = __expf(mcv - mg);
    lg += coef * lmb[(size_t)s * 128 + 64 + row];
    const float* Op = (s < 1536) ? Pn + (size_t)s * 4096
                                 : Ph + (size_t)(s - 1536) * 4096;
    const float* rp = Op + (size_t)row * 64 + c0;
#pragma unroll
    for (int g = 0; g < 4; g++) {
      float4 v;
      __builtin_memcpy(&v, rp + g * 4, 16);
      acc[g * 4 + 0] += coef * v.x;
      acc[g * 4 + 1] += coef * v.y;
      acc[g * 4 + 2] += coef * v.z;
      acc[g * 4 + 3] += coef * v.w;
    }
  }
  const float inv = 1.0f / fmaxf(lg, 1e-30f);
  const int q = qt * 64 + row;
  const size_t ob = (size_t)b * 2048 * 768 + h * 64 + (size_t)q * 768 + c0;
#pragma unroll
  for (int j = 0; j < 16; j++) O[ob + j] = f2bf(acc[j] * inv);
}

// ---------------------------------------------------------------------------
extern "C" void kernel_launch(void* const* d_in, const int* in_sizes, int n_in,
                              void* d_out, int out_size, void* d_ws,
                              size_t ws_size, hipStream_t stream) {
  (void)in_sizes; (void)n_in; (void)out_size; (void)ws_size;
  const float* x = (const float*)d_in[0];
  const void* mask = d_in[2];

  char* ws = (char*)d_ws;
  u16* Wb  = (u16*)(ws);                        // bf16 arena, 23599104 B
  u16* n1h = (u16*)(ws + 23599104);             // 4096x3072 bf16 (h1 / attn partials)
  u16* Qb  = (u16*)(ws + 48764928);             // 4096x768 (later n2)
  u16* Kb2 = (u16*)(ws + 55056384);             // 4096x768
  u16* Vb2 = (u16*)(ws + 61347840);             // 4096x768
  u16* att = (u16*)(ws + 67639296);             // 4096x768 att, later ht (x1536)
  u16* hs  = (u16*)(ws + 80222208);             // 4096x1536 (attn partial spill)
  float* mfl = (float*)(ws + 92805120);         // 768 floats
  float* x1 = (float*)d_out;                    // x / x1 fp32 live in d_out
  float* Pn = (float*)n1h;                      // 1536 partial slots x 4096 f32
  float* Ph = (float*)hs;                       // 192 slots + m/l at +786432 f32

  u16* Wq = Wb + 0,        *Wk = Wb + 589824,   *Wv = Wb + 1179648;
  u16* Wo = Wb + 1769472,  *w1 = Wb + 2359296,  *w1t = Wb + 4718592;
  u16* w1s = Wb + 5898240, *w2 = Wb + 7077888,  *w2t = Wb + 9437184;
  u16* w2s = Wb + 10616832;
  u16* n1w = Wb + 11796480, *n1b = Wb + 11797248;
  u16* n2w = Wb + 11798016, *n2b = Wb + 11798784;

  Segs sg;
  const int srcidx[14] = {3, 4, 5, 6, 7, 9, 11, 8, 10, 12, 13, 14, 15, 16};
  const int offs[14] = {0, 589824, 1179648, 1769472, 2359296, 4718592,
                        5898240, 7077888, 9437184, 10616832,
                        11796480, 11797248, 11798016, 11798784};
  const int ns[14] = {589824, 589824, 589824, 589824, 2359296, 1179648,
                      1179648, 2359296, 1179648, 1179648, 768, 768, 768, 768};
  const int mms[14] = {0, 0, 0, 0, 0, 1, 2, 0, 0, 0, 0, 0, 0, 0};
  for (int i = 0; i < 14; i++) {
    sg.src[i] = d_in[srcidx[i]];
    sg.off[i] = offs[i];
    sg.n[i] = ns[i];
    sg.mmode[i] = mms[i];
  }

  mask_conv_k<<<1, 256, 0, stream>>>(mask, mfl);
  convert_k<<<dim3(2304, 14), 256, 0, stream>>>(sg, Wb, mfl);

  // n1 = mink_norm(x); also seed d_out with x (residual base for Wo atomics)
  mink_norm_k<<<4096, 256, 0, stream>>>(x, mfl, n1w, n1b, n1h, x1);

  // Q,K,V fused (N=2304), XCD-swizzled
  GArgs qkv;
  qkv.s[0] = {Wq, Qb, 768, 6, 0};
  qkv.s[1] = {Wk, Kb2, 768, 6, 0};
  qkv.s[2] = {Wv, Vb2, 768, 6, 0};
  gemm128_fused<<<dim3(18, 32), 256, 0, stream>>>(n1h, 768, 768, qkv);

  qcorr_k<<<12288, 256, 0, stream>>>(Qb, mfl);

  // flash attention: 80 chunks/bh, partials into Pn/Ph, then merge
  flash_attn_k<<<dim3(80, 24), 256, 0, stream>>>(Qb, Kb2, Vb2, att, Pn, Ph);
  attn_merge_k<<<dim3(24, 24), 256, 0, stream>>>(Pn, Ph, att);

  // x1 = x + att @ Wo^T  (split-K x2 atomic into d_out holding x)
  gemm128_wo_splitk<<<dim3(6, 32, 2), 256, 0, stream>>>(att, Wo, x1);

  // n2 = mink_norm(x1) -> Qb (mask folded into FFN1 weights)
  mink_norm_k<<<4096, 256, 0, stream>>>(x1, mfl, n2w, n2b, Qb, nullptr);

  // FFN1 fused (N=6144): h1 = gelu(n2@w1^T), ht = silu(n2@w1t_m^T),
  // hs = gelu(n2@w1s_m^T), XCD-swizzled
  GArgs ffn1;
  ffn1.s[0] = {w1, n1h, 3072, 24, 2};
  ffn1.s[1] = {w1t, att, 1536, 12, 3};
  ffn1.s[2] = {w1s, hs, 1536, 12, 2};
  gemm128_fused<<<dim3(48, 32), 256, 0, stream>>>(Qb, 768, 768, ffn1);

  // out = x1 + 0.5*(h1@w2^T + ht@w2_t^T + hs@w2_s^T), split-K x4 atomic
  ffn2_splitk<<<dim3(6, 32, 4), 256, 0, stream>>>(n1h, att, hs, w2, w2t, w2s,
                                                  (float*)d_out);
}